// Round 10
// baseline (220.361 us; speedup 1.0000x reference)
//
#include <hip/hip_runtime.h>
#include <hip/hip_bf16.h>
#include <stdint.h>

// out = X @ Bbig + bias; X = (32768 x 1024) fp32 (real||imag)
//   n<512:  B[k][n] = Wr[n][k] (k<512), -Wi[n][k-512] (k>=512)
//   n>=512: B[k][n] = Wi[n-512][k] (k<512), Wr[n-512][k-512] (k>=512)
//
// R10: ZERO-LDS GEMM. Evidence from R1-R9: perf tracks LDS bytes/FLOP
// (R3/6/7 identical across 3 schedules; R1/R9 worse exactly in proportion)
// => LDS pipe is the serialized resource. Fix: both operands stored
// FRAGMENT-MAJOR by the prepass, each lane's 16B MFMA operand is a
// contiguous coalesced global load (A: L3-resident 64MiB image read once;
// B: L2-resident 2MiB image). No LDS, no barriers, no manual waitcnt.
// In-place frag reload (WAR on MFMA sources) forces the compiler pipeline:
// phase-A (kk=0) MFMAs overlap kk=1 loads; steady-state wait = vmcnt(12).
//
// Fragment-major layouts (lane = lq*16+lr, lr=lane&15, lq=lane>>4):
//  A chunk ci = ((g16*16 + t)*2 + kk)*64 + lane, 16B each:
//    = Afp16[row = g16*16 + lr][k = t*64 + kk*32 + lq*8 .. +8]
//  B chunk ci = ((ng*16 + t)*8 + j*2 + kk)*64 + lane:
//    = B^T[n = ng*64 + j*16 + lr][k = t*64 + kk*32 + lq*8 .. +8]

typedef _Float16 half8 __attribute__((ext_vector_type(8)));
typedef float f32x4 __attribute__((ext_vector_type(4)));

#define PRIO1() __builtin_amdgcn_s_setprio(1)
#define PRIO0() __builtin_amdgcn_s_setprio(0)

// ---------------- Kernel 1: B image, fragment-major ----------------
__global__ void build_bt(const float* __restrict__ G1R, const float* __restrict__ G2R,
                         const float* __restrict__ G1I, const float* __restrict__ G2I,
                         _Float16* __restrict__ BT) {
  int idx = blockIdx.x * 256 + threadIdx.x;  // 0 .. 1M-1 (one fp16 each)
  int e    = idx & 7;
  int lane = (idx >> 3) & 63;
  int kk   = (idx >> 9) & 1;
  int j    = (idx >> 10) & 3;
  int t    = (idx >> 12) & 15;
  int ng   = idx >> 16;                      // 0..15
  int n = ng * 64 + j * 16 + (lane & 15);
  int k = t * 64 + kk * 32 + (lane >> 4) * 8 + e;
  int o = n & 511, i = k & 511;
  bool imagOut = n >= 512, kHi = k >= 512;
  const float* G1; const float* G2; float sign = 1.0f;
  if (imagOut == kHi) { G1 = G1R; G2 = G2R; }
  else { G1 = G1I; G2 = G2I; if (!imagOut) sign = -1.0f; }
  int b = o >> 4, ee = o & 15, d = i >> 4, g = i & 15;
  float w = 0.0f;
#pragma unroll
  for (int c = 0; c < 4; ++c)
    w += G1[b * 128 + c * 32 + d] * G2[c * 256 + ee * 16 + g];
  BT[idx] = (_Float16)(sign * w);
}

// ---------------- Kernel 2: A image, fragment-major (x fp32 -> fp16) --------
__global__ __launch_bounds__(256) void build_at(const float* __restrict__ X,
                                                _Float16* __restrict__ Aimg) {
  int ci = blockIdx.x * 256 + threadIdx.x;   // 0 .. 4,194,303 (16B chunk each)
  int lane = ci & 63;
  int kk   = (ci >> 6) & 1;
  int t    = (ci >> 7) & 15;
  int g16  = ci >> 11;                       // 0..2047
  int row = g16 * 16 + (lane & 15);
  int k0  = t * 64 + kk * 32 + (lane >> 4) * 8;
  const float* s = X + (size_t)row * 1024 + k0;
  float4 v0 = *(const float4*)s;
  float4 v1 = *(const float4*)(s + 4);
  half8 h = { (_Float16)v0.x, (_Float16)v0.y, (_Float16)v0.z, (_Float16)v0.w,
              (_Float16)v1.x, (_Float16)v1.y, (_Float16)v1.z, (_Float16)v1.w };
  *(half8*)((char*)Aimg + (size_t)ci * 16) = h;
}

// ---------------- Kernel 3: zero-LDS GEMM ----------------
// 1024 blocks x 256 thr; block = 4 M-stacked waves (512 rows) x 64 cols.
// XCD swizzle: xcd=bid&7 owns ng = xcd*2 + ((bid>>3)>>6)  -> B panel L2-local.
__global__ __launch_bounds__(256, 2) void tt_gemm(
    const _Float16* __restrict__ Aimg, const _Float16* __restrict__ Bimg,
    const float* __restrict__ bias_r, const float* __restrict__ bias_i,
    float* __restrict__ C) {
  const int tid = threadIdx.x, bid = blockIdx.x;
  const int w = tid >> 6, lane = tid & 63;
  const int lr = lane & 15, lq = lane >> 4;
  const int lb = bid >> 3;
  const int ng  = (bid & 7) * 2 + (lb >> 6);   // 0..15: 64-col group
  const int mtb = lb & 63;                     // 0..63: 512-row group
  const int g16b = (mtb * 4 + w) * 8;          // this wave's first 16-row group

  const char* Ab = (const char*)Aimg + (size_t)lane * 16;
  const char* Bb = (const char*)Bimg + (size_t)lane * 16;

  f32x4 acc[8][4] = {};
  half8 afr[8][2], bfr[4][2];

  auto aaddr = [&](int mf, int t, int kk) {
    return (const half8*)(Ab + ((size_t)(((g16b + mf) * 16 + t) * 2 + kk) << 10));
  };
  auto baddr = [&](int j, int t, int kk) {
    return (const half8*)(Bb + ((size_t)((ng * 16 + t) * 8 + j * 2 + kk) << 10));
  };

  // prologue: all 24 frags of tile 0
#pragma unroll
  for (int mf = 0; mf < 8; ++mf) {
    afr[mf][0] = *aaddr(mf, 0, 0);
    afr[mf][1] = *aaddr(mf, 0, 1);
  }
#pragma unroll
  for (int j = 0; j < 4; ++j) {
    bfr[j][0] = *baddr(j, 0, 0);
    bfr[j][1] = *baddr(j, 0, 1);
  }

  for (int t = 0; t < 16; ++t) {
    // phase A: kk=0 (32 MFMA); then reload kk=0 frags for t+1 (WAR-ordered)
    PRIO1();
#pragma unroll
    for (int mf = 0; mf < 8; ++mf)
#pragma unroll
      for (int j = 0; j < 4; ++j)
        acc[mf][j] = __builtin_amdgcn_mfma_f32_16x16x32_f16(
            afr[mf][0], bfr[j][0], acc[mf][j], 0, 0, 0);
    PRIO0();
    if (t < 15) {
#pragma unroll
      for (int mf = 0; mf < 8; ++mf) afr[mf][0] = *aaddr(mf, t + 1, 0);
#pragma unroll
      for (int j = 0; j < 4; ++j)    bfr[j][0] = *baddr(j, t + 1, 0);
    }
    // phase B: kk=1 (32 MFMA); then reload kk=1 frags for t+1
    PRIO1();
#pragma unroll
    for (int mf = 0; mf < 8; ++mf)
#pragma unroll
      for (int j = 0; j < 4; ++j)
        acc[mf][j] = __builtin_amdgcn_mfma_f32_16x16x32_f16(
            afr[mf][1], bfr[j][1], acc[mf][j], 0, 0, 0);
    PRIO0();
    if (t < 15) {
#pragma unroll
      for (int mf = 0; mf < 8; ++mf) afr[mf][1] = *aaddr(mf, t + 1, 1);
#pragma unroll
      for (int j = 0; j < 4; ++j)    bfr[j][1] = *baddr(j, t + 1, 1);
    }
  }

  // epilogue: C/D layout col=lr, row=lq*4+r
  const int row0 = (mtb * 4 + w) * 128;
  const int col0 = ng * 64;
#pragma unroll
  for (int j = 0; j < 4; ++j) {
    int col = col0 + j * 16 + lr;
    float bias = (col < 512) ? bias_r[col] : bias_i[col - 512];
#pragma unroll
    for (int mf = 0; mf < 8; ++mf) {
      int r0 = row0 + mf * 16 + lq * 4;
#pragma unroll
      for (int r = 0; r < 4; ++r)
        C[(size_t)(r0 + r) * 1024 + col] = acc[mf][j][r] + bias;
    }
  }
}

extern "C" void kernel_launch(void* const* d_in, const int* in_sizes, int n_in,
                              void* d_out, int out_size, void* d_ws, size_t ws_size,
                              hipStream_t stream) {
  const float* x   = (const float*)d_in[0];
  const float* G1R = (const float*)d_in[1];
  const float* G2R = (const float*)d_in[2];
  const float* G1I = (const float*)d_in[3];
  const float* G2I = (const float*)d_in[4];
  const float* br  = (const float*)d_in[5];
  const float* bi  = (const float*)d_in[6];
  float* out = (float*)d_out;

  _Float16* Bimg = (_Float16*)d_ws;                          // 2 MiB
  _Float16* Aimg = (_Float16*)((char*)d_ws + (2u << 20));    // 64 MiB

  build_bt<<<4096, 256, 0, stream>>>(G1R, G2R, G1I, G2I, Bimg);
  build_at<<<16384, 256, 0, stream>>>(x, Aimg);
  tt_gemm<<<1024, 256, 0, stream>>>(Aimg, Bimg, br, bi, out);
}

// Round 11
// 124.460 us; speedup vs baseline: 1.7705x; 1.7705x over previous
//
#include <hip/hip_runtime.h>
#include <hip/hip_bf16.h>
#include <stdint.h>

// out = X @ Bbig + bias; X = (32768 x 1024) fp32 (real||imag)
//   n<512:  B[k][n] = Wr[n][k] (k<512), -Wi[n][k-512] (k>=512)
//   n>=512: B[k][n] = Wi[n-512][k] (k<512), Wr[n-512][k-512] (k>=512)
// R11: split path (swizzled fp16 images for A and B) + OVERLAPPED schedule.
// Evidence R1-R10: all LDS variants alternate {ds_read phase | MFMA phase}
// at the CU level (lgkm0+barrier between) -> util cap ~30% = measured.
// New loop overlaps LDS reads with MFMA within each wave via the two
// K-halves: read kk1(t) under MFMA kk0(t); read kk0(t+1) + issue stage(t+2)
// under MFMA kk1(t). ONE barrier + ONE lgkmcnt(0) + ONE vmcnt(0) per K-tile.

typedef _Float16 half8 __attribute__((ext_vector_type(8)));
typedef _Float16 half4v __attribute__((ext_vector_type(4)));
typedef float f32x4 __attribute__((ext_vector_type(4)));

typedef __attribute__((address_space(3))) void* lds_ptr_t;
typedef const __attribute__((address_space(1))) void* gbl_ptr_t;

__device__ __forceinline__ void gload_lds16(const void* g, void* s) {
  // lane l's 16B from per-lane g land at (wave-uniform) s + l*16
  __builtin_amdgcn_global_load_lds((gbl_ptr_t)g, (lds_ptr_t)s, 16, 0, 0);
}

#define BARF() asm volatile("s_barrier" ::: "memory")
#define LGKM0() asm volatile("s_waitcnt lgkmcnt(0)" ::: "memory")
#define VMC8() asm volatile("s_waitcnt vmcnt(8)" ::: "memory")
#define VMC0() asm volatile("s_waitcnt vmcnt(0)" ::: "memory")
#define PRIO1() __builtin_amdgcn_s_setprio(1)
#define PRIO0() __builtin_amdgcn_s_setprio(0)

// Tile byte layout (32 KB per 256-row x 64-col fp16 tile):
//   byte = row*128 + ((kcol*2) ^ ((row&7)<<4))   -- XOR bank swizzle

// ---------------- Kernel 1: swizzled B image (validated r2-r7) ----------------
__global__ void build_bt(const float* __restrict__ G1R, const float* __restrict__ G2R,
                         const float* __restrict__ G1I, const float* __restrict__ G2I,
                         _Float16* __restrict__ BTimg) {
  int idx = blockIdx.x * 256 + threadIdx.x;  // 0 .. 1M-1
  int kcol = idx & 63;
  int row  = (idx >> 6) & 255;
  int kt   = (idx >> 14) & 15;
  int nt   = idx >> 18;
  int n = nt * 256 + row;
  int k = kt * 64 + kcol;
  int o = n & 511, i = k & 511;
  bool imagOut = n >= 512, kHi = k >= 512;
  const float* G1; const float* G2; float sign = 1.0f;
  if (imagOut == kHi) { G1 = G1R; G2 = G2R; }
  else { G1 = G1I; G2 = G2I; if (!imagOut) sign = -1.0f; }
  int b = o >> 4, e = o & 15, d = i >> 4, g = i & 15;
  float w = 0.0f;
#pragma unroll
  for (int c = 0; c < 4; ++c)
    w += G1[b * 128 + c * 32 + d] * G2[c * 256 + e * 16 + g];
  size_t byteoff = ((size_t)(nt * 16 + kt) << 15) + (size_t)row * 128
                 + ((kcol * 2) ^ ((row & 7) << 4));
  *(_Float16*)((char*)BTimg + byteoff) = (_Float16)(sign * w);
}

// ---------------- Kernel 2: X fp32 -> swizzled fp16 A image (validated) -------
__global__ __launch_bounds__(256) void build_at(const float* __restrict__ A,
                                                _Float16* __restrict__ Aimg) {
  const int tid = threadIdx.x;
  const int kt = blockIdx.x & 15, mt = blockIdx.x >> 4;
  const float* src = A + (size_t)mt * 256 * 1024 + kt * 64;
  char* dst = (char*)Aimg + ((size_t)(mt * 16 + kt) << 15);
  const int cg = tid & 15;        // col group (4 floats)
  const int rb = tid >> 4;        // row base
#pragma unroll
  for (int r = 0; r < 16; ++r) {
    int row = rb + r * 16;        // 0..255
    float4 v = *(const float4*)(src + (size_t)row * 1024 + cg * 4);
    half4v h = { (_Float16)v.x, (_Float16)v.y, (_Float16)v.z, (_Float16)v.w };
    *(half4v*)(dst + row * 128 + ((cg * 8) ^ ((row & 7) << 4))) = h;
  }
}

// ---------------- Kernel 3: GEMM, overlapped 1-barrier schedule ----------------
__global__ __launch_bounds__(512, 2) void tt_gemm(
    const _Float16* __restrict__ Aimg, const _Float16* __restrict__ Bimg,
    const float* __restrict__ bias_r, const float* __restrict__ bias_i,
    float* __restrict__ C) {
  __shared__ __align__(16) _Float16 Als[2][16384];  // 32KB/buf, swizzled
  __shared__ __align__(16) _Float16 Bls[2][16384];

  const int tid = threadIdx.x;
  const int bid = blockIdx.x;
  // XCD swizzle (512 % 8 == 0): 64 contiguous per XCD, nt fastest (A L2 reuse)
  const int bid2 = (bid & 7) * 64 + (bid >> 3);
  const int mt = bid2 >> 2, nt = bid2 & 3;

  const int lane = tid & 63, wid = tid >> 6;
  const int wm = wid >> 2, wn = wid & 3;   // wave -> 128(M) x 64(N) C subtile
  const int lr = lane & 15, lq = lane >> 4;

  f32x4 acc[8][4] = {};
  half8 afr0[8], afr1[8], bfr0[4], bfr1[4];  // named kk sets (static idx)

  const char* Abase = (const char*)Aimg + ((size_t)mt << 19);  // 16 tiles*32KB
  const char* Bbase = (const char*)Bimg + ((size_t)nt << 19);
  const int qoff = wid * 1024 + lane * 16;

  auto stageT = [&](int t, _Float16* Abuf, _Float16* Bbuf) {  // 8 gload/wave
    const char* sa = Abase + ((size_t)t << 15) + qoff;
    const char* sb = Bbase + ((size_t)t << 15) + qoff;
#pragma unroll
    for (int q = 0; q < 4; ++q)
      gload_lds16(sa + q * 8192, (char*)Abuf + q * 8192 + wid * 1024);
#pragma unroll
    for (int q = 0; q < 4; ++q)
      gload_lds16(sb + q * 8192, (char*)Bbuf + q * 8192 + wid * 1024);
  };
  auto readK0 = [&](const _Float16* Ab, const _Float16* Bb) {  // kk=0 frags
#pragma unroll
    for (int mf = 0; mf < 8; ++mf) {
      int row = wm * 128 + mf * 16 + lr;
      afr0[mf] = *(const half8*)((const char*)Ab + row * 128 + ((lq * 16) ^ ((row & 7) << 4)));
    }
#pragma unroll
    for (int j = 0; j < 4; ++j) {
      int row = wn * 64 + j * 16 + lr;
      bfr0[j] = *(const half8*)((const char*)Bb + row * 128 + ((lq * 16) ^ ((row & 7) << 4)));
    }
  };
  auto readK1 = [&](const _Float16* Ab, const _Float16* Bb) {  // kk=1 frags
#pragma unroll
    for (int mf = 0; mf < 8; ++mf) {
      int row = wm * 128 + mf * 16 + lr;
      afr1[mf] = *(const half8*)((const char*)Ab + row * 128 + (((64 + lq * 16) & 127) ^ ((row & 7) << 4)));
    }
#pragma unroll
    for (int j = 0; j < 4; ++j) {
      int row = wn * 64 + j * 16 + lr;
      bfr1[j] = *(const half8*)((const char*)Bb + row * 128 + (((64 + lq * 16) & 127) ^ ((row & 7) << 4)));
    }
  };
  auto mmaH = [&](half8 (&af)[8], half8 (&bf)[4]) {  // 32 MFMA (one K-half)
#pragma unroll
    for (int mf = 0; mf < 8; ++mf)
#pragma unroll
      for (int j = 0; j < 4; ++j)
        acc[mf][j] = __builtin_amdgcn_mfma_f32_16x16x32_f16(
            af[mf], bf[j], acc[mf][j], 0, 0, 0);
  };

  // ---- prologue: T0,T1 staged; T1 stays in flight; kk0(T0) frags loaded ----
  stageT(0, Als[0], Bls[0]);   // 8 vmem (oldest)
  stageT(1, Als[1], Bls[1]);   // 8 vmem
  VMC8();                      // T0 landed; T1 in flight
  BARF();
  readK0(Als[0], Bls[0]);

  // ---- main loop: 16 K-tiles, overlapped ----
  for (int t = 0; t < 16; ++t) {
    const int c = t & 1;
    // A: kk1 frag reads of tile t (12 ds_read_b128, overlap next MFMAs)
    readK1(Als[c], Bls[c]);
    // B: MFMA on kk0 frags (read last iteration under MFMA kk1)
    PRIO1(); mmaH(afr0, bfr0); PRIO0();
    // C: my reads of buf c done; stage(t+1) landed chip-wide; sync
    LGKM0(); VMC0(); BARF();
    // D: kk0 frags of t+1 from the buffer staged as t+1 (overlap MFMA kk1)
    if (t < 15) readK0(Als[c ^ 1], Bls[c ^ 1]);
    // E: issue stage(t+2) into freed buf c (waited at C of t+1)
    if (t < 14) stageT(t + 2, Als[c], Bls[c]);
    // F: MFMA on kk1 frags
    PRIO1(); mmaH(afr1, bfr1); PRIO0();
  }

  // ---- epilogue: C/D layout col=lr, row=lq*4+r ----
  const int row0 = mt * 256, col0 = nt * 256;
#pragma unroll
  for (int fn = 0; fn < 4; ++fn) {
    int col = col0 + wn * 64 + fn * 16 + lr;
    float bias = (col < 512) ? bias_r[col] : bias_i[col - 512];
#pragma unroll
    for (int fm = 0; fm < 8; ++fm) {
      int r0 = row0 + wm * 128 + fm * 16 + lq * 4;
#pragma unroll
      for (int r = 0; r < 4; ++r)
        C[(size_t)(r0 + r) * 1024 + col] = acc[fm][fn][r] + bias;
    }
  }
}

extern "C" void kernel_launch(void* const* d_in, const int* in_sizes, int n_in,
                              void* d_out, int out_size, void* d_ws, size_t ws_size,
                              hipStream_t stream) {
  const float* x   = (const float*)d_in[0];
  const float* G1R = (const float*)d_in[1];
  const float* G2R = (const float*)d_in[2];
  const float* G1I = (const float*)d_in[3];
  const float* G2I = (const float*)d_in[4];
  const float* br  = (const float*)d_in[5];
  const float* bi  = (const float*)d_in[6];
  float* out = (float*)d_out;

  _Float16* Bimg = (_Float16*)d_ws;                          // 2 MiB
  _Float16* Aimg = (_Float16*)((char*)d_ws + (2u << 20));    // 64 MiB

  build_bt<<<4096, 256, 0, stream>>>(G1R, G2R, G1I, G2I, Bimg);
  build_at<<<2048, 256, 0, stream>>>(x, Aimg);
  tt_gemm<<<512, 512, 0, stream>>>(Aimg, Bimg, br, bi, out);
}

// Round 12
// 122.465 us; speedup vs baseline: 1.7994x; 1.0163x over previous
//
#include <hip/hip_runtime.h>
#include <hip/hip_bf16.h>
#include <stdint.h>

// out = X @ Bbig + bias; X = (32768 x 1024) fp32 (real||imag)
//   n<512:  B[k][n] = Wr[n][k] (k<512), -Wi[n][k-512] (k>=512)
//   n>=512: B[k][n] = Wi[n-512][k] (k<512), Wr[n-512][k-512] (k>=512)
// R12 = R11 (overlapped 1-barrier loop, best: 88us GEMM) + LDS-staged
// float4 epilogue. R11's epilogue was 128 scalar dword stores/thread at
// 4KB stride (partial 64B lines, WRITE 150MB vs 134 ideal). New epilogue
// stages acc into LDS (stride 260 floats: bank-pair-free, 16B aligned)
// and stores dense float4 runs (one wave-store = 8 full cache lines).

typedef _Float16 half8 __attribute__((ext_vector_type(8)));
typedef _Float16 half4v __attribute__((ext_vector_type(4)));
typedef float f32x4 __attribute__((ext_vector_type(4)));

typedef __attribute__((address_space(3))) void* lds_ptr_t;
typedef const __attribute__((address_space(1))) void* gbl_ptr_t;

__device__ __forceinline__ void gload_lds16(const void* g, void* s) {
  // lane l's 16B from per-lane g land at (wave-uniform) s + l*16
  __builtin_amdgcn_global_load_lds((gbl_ptr_t)g, (lds_ptr_t)s, 16, 0, 0);
}

#define BARF() asm volatile("s_barrier" ::: "memory")
#define LGKM0() asm volatile("s_waitcnt lgkmcnt(0)" ::: "memory")
#define VMC8() asm volatile("s_waitcnt vmcnt(8)" ::: "memory")
#define VMC0() asm volatile("s_waitcnt vmcnt(0)" ::: "memory")
#define PRIO1() __builtin_amdgcn_s_setprio(1)
#define PRIO0() __builtin_amdgcn_s_setprio(0)

// Tile byte layout (32 KB per 256-row x 64-col fp16 tile):
//   byte = row*128 + ((kcol*2) ^ ((row&7)<<4))   -- XOR bank swizzle

// ---------------- Kernel 1: swizzled B image (validated r2-r11) ---------------
__global__ void build_bt(const float* __restrict__ G1R, const float* __restrict__ G2R,
                         const float* __restrict__ G1I, const float* __restrict__ G2I,
                         _Float16* __restrict__ BTimg) {
  int idx = blockIdx.x * 256 + threadIdx.x;  // 0 .. 1M-1
  int kcol = idx & 63;
  int row  = (idx >> 6) & 255;
  int kt   = (idx >> 14) & 15;
  int nt   = idx >> 18;
  int n = nt * 256 + row;
  int k = kt * 64 + kcol;
  int o = n & 511, i = k & 511;
  bool imagOut = n >= 512, kHi = k >= 512;
  const float* G1; const float* G2; float sign = 1.0f;
  if (imagOut == kHi) { G1 = G1R; G2 = G2R; }
  else { G1 = G1I; G2 = G2I; if (!imagOut) sign = -1.0f; }
  int b = o >> 4, e = o & 15, d = i >> 4, g = i & 15;
  float w = 0.0f;
#pragma unroll
  for (int c = 0; c < 4; ++c)
    w += G1[b * 128 + c * 32 + d] * G2[c * 256 + e * 16 + g];
  size_t byteoff = ((size_t)(nt * 16 + kt) << 15) + (size_t)row * 128
                 + ((kcol * 2) ^ ((row & 7) << 4));
  *(_Float16*)((char*)BTimg + byteoff) = (_Float16)(sign * w);
}

// ---------------- Kernel 2: X fp32 -> swizzled fp16 A image (validated) -------
__global__ __launch_bounds__(256) void build_at(const float* __restrict__ A,
                                                _Float16* __restrict__ Aimg) {
  const int tid = threadIdx.x;
  const int kt = blockIdx.x & 15, mt = blockIdx.x >> 4;
  const float* src = A + (size_t)mt * 256 * 1024 + kt * 64;
  char* dst = (char*)Aimg + ((size_t)(mt * 16 + kt) << 15);
  const int cg = tid & 15;        // col group (4 floats)
  const int rb = tid >> 4;        // row base
#pragma unroll
  for (int r = 0; r < 16; ++r) {
    int row = rb + r * 16;        // 0..255
    float4 v = *(const float4*)(src + (size_t)row * 1024 + cg * 4);
    half4v h = { (_Float16)v.x, (_Float16)v.y, (_Float16)v.z, (_Float16)v.w };
    *(half4v*)(dst + row * 128 + ((cg * 8) ^ ((row & 7) << 4))) = h;
  }
}

// ---------------- Kernel 3: GEMM, overlapped loop + LDS float4 epilogue -------
__global__ __launch_bounds__(512, 2) void tt_gemm(
    const _Float16* __restrict__ Aimg, const _Float16* __restrict__ Bimg,
    const float* __restrict__ bias_r, const float* __restrict__ bias_i,
    float* __restrict__ C) {
  __shared__ __align__(16) _Float16 Als[2][16384];  // 32KB/buf, swizzled
  __shared__ __align__(16) _Float16 Bls[2][16384];

  const int tid = threadIdx.x;
  const int bid = blockIdx.x;
  // XCD swizzle (512 % 8 == 0): 64 contiguous per XCD, nt fastest (A L2 reuse)
  const int bid2 = (bid & 7) * 64 + (bid >> 3);
  const int mt = bid2 >> 2, nt = bid2 & 3;

  const int lane = tid & 63, wid = tid >> 6;
  const int wm = wid >> 2, wn = wid & 3;   // wave -> 128(M) x 64(N) C subtile
  const int lr = lane & 15, lq = lane >> 4;

  f32x4 acc[8][4] = {};
  half8 afr0[8], afr1[8], bfr0[4], bfr1[4];  // named kk sets (static idx)

  const char* Abase = (const char*)Aimg + ((size_t)mt << 19);  // 16 tiles*32KB
  const char* Bbase = (const char*)Bimg + ((size_t)nt << 19);
  const int qoff = wid * 1024 + lane * 16;

  auto stageT = [&](int t, _Float16* Abuf, _Float16* Bbuf) {  // 8 gload/wave
    const char* sa = Abase + ((size_t)t << 15) + qoff;
    const char* sb = Bbase + ((size_t)t << 15) + qoff;
#pragma unroll
    for (int q = 0; q < 4; ++q)
      gload_lds16(sa + q * 8192, (char*)Abuf + q * 8192 + wid * 1024);
#pragma unroll
    for (int q = 0; q < 4; ++q)
      gload_lds16(sb + q * 8192, (char*)Bbuf + q * 8192 + wid * 1024);
  };
  auto readK0 = [&](const _Float16* Ab, const _Float16* Bb) {  // kk=0 frags
#pragma unroll
    for (int mf = 0; mf < 8; ++mf) {
      int row = wm * 128 + mf * 16 + lr;
      afr0[mf] = *(const half8*)((const char*)Ab + row * 128 + ((lq * 16) ^ ((row & 7) << 4)));
    }
#pragma unroll
    for (int j = 0; j < 4; ++j) {
      int row = wn * 64 + j * 16 + lr;
      bfr0[j] = *(const half8*)((const char*)Bb + row * 128 + ((lq * 16) ^ ((row & 7) << 4)));
    }
  };
  auto readK1 = [&](const _Float16* Ab, const _Float16* Bb) {  // kk=1 frags
#pragma unroll
    for (int mf = 0; mf < 8; ++mf) {
      int row = wm * 128 + mf * 16 + lr;
      afr1[mf] = *(const half8*)((const char*)Ab + row * 128 + ((64 + lq * 16) ^ ((row & 7) << 4)));
    }
#pragma unroll
    for (int j = 0; j < 4; ++j) {
      int row = wn * 64 + j * 16 + lr;
      bfr1[j] = *(const half8*)((const char*)Bb + row * 128 + ((64 + lq * 16) ^ ((row & 7) << 4)));
    }
  };
  auto mmaH = [&](half8 (&af)[8], half8 (&bf)[4]) {  // 32 MFMA (one K-half)
#pragma unroll
    for (int mf = 0; mf < 8; ++mf)
#pragma unroll
      for (int j = 0; j < 4; ++j)
        acc[mf][j] = __builtin_amdgcn_mfma_f32_16x16x32_f16(
            af[mf], bf[j], acc[mf][j], 0, 0, 0);
  };

  // ---- prologue: T0,T1 staged; T1 stays in flight; kk0(T0) frags loaded ----
  stageT(0, Als[0], Bls[0]);   // 8 vmem (oldest)
  stageT(1, Als[1], Bls[1]);   // 8 vmem
  VMC8();                      // T0 landed; T1 in flight
  BARF();
  readK0(Als[0], Bls[0]);

  // ---- main loop: 16 K-tiles, overlapped (R11, unchanged) ----
  for (int t = 0; t < 16; ++t) {
    const int c = t & 1;
    readK1(Als[c], Bls[c]);                 // A: kk1 reads overlap next MFMAs
    PRIO1(); mmaH(afr0, bfr0); PRIO0();     // B: MFMA kk0
    LGKM0(); VMC0(); BARF();                // C: single sync/tile
    if (t < 15) readK0(Als[c ^ 1], Bls[c ^ 1]);   // D: kk0(t+1) under MFMA kk1
    if (t < 14) stageT(t + 2, Als[c], Bls[c]);    // E: deep stage
    PRIO1(); mmaH(afr1, bfr1); PRIO0();     // F: MFMA kk1
  }

  // ---- epilogue: LDS-staged transposed float4 stores ----
  // fbuf stride 260 floats: 260*4=1040 B (16B-aligned rows), banks spread.
  const int row0 = mt * 256, col0 = nt * 256;
  float* fbuf = (float*)&Als[0][0];         // 64 KB available (Als+Bls region is 128KB; use first 33KB)
  float bcol[4];
#pragma unroll
  for (int fn = 0; fn < 4; ++fn) {
    int col = col0 + wn * 64 + fn * 16 + lr;
    bcol[fn] = (col < 512) ? bias_r[col] : bias_i[col - 512];
  }
  const int lrow_base = wm * 16 + lq * 4;   // 0..31 local row
  const int lcol = wn * 64 + lr;            // + fn*16
#pragma unroll
  for (int fm = 0; fm < 8; ++fm) {
    BARF();   // previous round's reads done (first: entry sync)
#pragma unroll
    for (int fn = 0; fn < 4; ++fn)
#pragma unroll
      for (int r = 0; r < 4; ++r)
        fbuf[(lrow_base + r) * 260 + lcol + fn * 16] = acc[fm][fn][r] + bcol[fn];
    BARF();
#pragma unroll
    for (int s = 0; s < 4; ++s) {
      int idx = tid + s * 512;              // 0..2047 float4 slots
      int lrow = idx >> 6, c4 = idx & 63;
      int grow = row0 + (lrow >> 4) * 128 + fm * 16 + (lrow & 15);
      *(float4*)&C[(size_t)grow * 1024 + col0 + c4 * 4] =
          *(const float4*)&fbuf[lrow * 260 + c4 * 4];
    }
  }
}

extern "C" void kernel_launch(void* const* d_in, const int* in_sizes, int n_in,
                              void* d_out, int out_size, void* d_ws, size_t ws_size,
                              hipStream_t stream) {
  const float* x   = (const float*)d_in[0];
  const float* G1R = (const float*)d_in[1];
  const float* G2R = (const float*)d_in[2];
  const float* G1I = (const float*)d_in[3];
  const float* G2I = (const float*)d_in[4];
  const float* br  = (const float*)d_in[5];
  const float* bi  = (const float*)d_in[6];
  float* out = (float*)d_out;

  _Float16* Bimg = (_Float16*)d_ws;                          // 2 MiB
  _Float16* Aimg = (_Float16*)((char*)d_ws + (2u << 20));    // 64 MiB

  build_bt<<<4096, 256, 0, stream>>>(G1R, G2R, G1I, G2I, Bimg);
  build_at<<<2048, 256, 0, stream>>>(x, Aimg);
  tt_gemm<<<512, 512, 0, stream>>>(Aimg, Bimg, br, bi, out);
}